// Round 17
// baseline (158.044 us; speedup 1.0000x reference)
//
#include <hip/hip_runtime.h>

#define SEQ 4096
#define DMODEL 1024
#define HEADS 16
#define HD 64
#define NQKV 3072

typedef __attribute__((ext_vector_type(8))) __bf16 bf16x8;
typedef __attribute__((ext_vector_type(4))) __bf16 bf16x4;
typedef __attribute__((ext_vector_type(8))) short short8;
typedef __attribute__((ext_vector_type(4))) float f32x4;
typedef __attribute__((ext_vector_type(16))) float f32x16;
typedef __attribute__((ext_vector_type(4))) unsigned int u32x4;

__device__ __forceinline__ unsigned short f2bf(float f) {
    unsigned u = __builtin_bit_cast(unsigned, f);
    return (unsigned short)((u + 0x7fffu + ((u >> 16) & 1u)) >> 16);
}
__device__ __forceinline__ float bf2f(unsigned short h) {
    return __builtin_bit_cast(float, (unsigned)h << 16);
}
__device__ __forceinline__ unsigned cvt_pk_bf16(float lo, float hi) {
    unsigned r;
    asm("v_cvt_pk_bf16_f32 %0, %1, %2" : "=v"(r) : "v"(lo), "v"(hi));
    return r;
}

__device__ __forceinline__ void gload16(const void* g, void* l) {
    __builtin_amdgcn_global_load_lds(
        (const __attribute__((address_space(1))) unsigned int*)g,
        (__attribute__((address_space(3))) unsigned int*)l, 16, 0, 0);
}

// task table per head, LPT (length-descending). bit6=split, bit5=khalf, bits0-4=qtile
#define TS(qt, kh) (0x40 | ((kh) << 5) | (qt))
__device__ __constant__ unsigned char TASKS[48] = {
    TS(31,0), TS(31,1), TS(30,0), 15,
    TS(30,1), TS(29,0), TS(29,1), TS(28,0), 14,
    TS(28,1), TS(27,0), TS(27,1), TS(26,0), 13,
    TS(26,1), TS(25,0), TS(25,1), TS(24,0), 12,
    TS(24,1), TS(23,0), TS(23,1), TS(22,0), 11,
    TS(22,1), TS(21,0), TS(21,1), TS(20,0), 10,
    TS(20,1), TS(19,0), TS(19,1), TS(18,0), 9,
    TS(18,1), TS(17,0), TS(17,1), TS(16,0), 8,
    TS(16,1), 7,
    6, 5, 4, 3, 2, 1, 0
};

// ---------------- fp32 -> bf16 convert, all three tensors in one launch ----------------
__global__ void f2bf_all(const float* __restrict__ x, const float* __restrict__ wqkv,
                         const float* __restrict__ wo, unsigned short* __restrict__ dst) {
    const int N0 = SEQ * DMODEL / 4;
    const int N1 = N0 + NQKV * DMODEL / 4;
    const int NT = N1 + DMODEL * DMODEL / 4;
    int i = blockIdx.x * 256 + threadIdx.x;
    int stride = gridDim.x * 256;
    for (; i < NT; i += stride) {
        const float4* src;
        if (i < N0)      src = reinterpret_cast<const float4*>(x) + i;
        else if (i < N1) src = reinterpret_cast<const float4*>(wqkv) + (i - N0);
        else             src = reinterpret_cast<const float4*>(wo) + (i - N1);
        float4 f = *src;
        ushort4 o;
        o.x = f2bf(f.x); o.y = f2bf(f.y); o.z = f2bf(f.z); o.w = f2bf(f.w);
        reinterpret_cast<ushort4*>(dst)[i] = o;
    }
}

// ---------------- bf16 GEMM, C = A(MxK) * B(NxK)^T ----------------
template <int EPI>
__global__ __launch_bounds__(256) void gemm_bt(const unsigned short* __restrict__ A,
                                               const unsigned short* __restrict__ B,
                                               float* __restrict__ outF,
                                               unsigned short* __restrict__ outB,
                                               int M, int N, int K) {
    alignas(16) __shared__ unsigned short a_lds[2][128 * 32];
    alignas(16) __shared__ unsigned short b_lds[2][128 * 32];
    const int tid = threadIdx.x;
    const int wave = tid >> 6, lane = tid & 63;
    const int l16 = lane & 15, g = lane >> 4;
    const int wr = wave >> 1, wc = wave & 1;
    const int bm = blockIdx.x, bn = blockIdx.y;

    const int lrow = lane >> 2;
    const int lcol = (lane & 3) * 8;

    const unsigned short* Ag = A + (size_t)(bm * 128 + lrow) * K + lcol;
    const unsigned short* Bg = B + (size_t)(bn * 128 + lrow) * K + lcol;

    f32x4 acc[4][4] = {};
    const int NS = K / 32;

    auto STAGE = [&](int b, int ks) {
#pragma unroll
        for (int j = 0; j < 2; ++j) {
            int chunk = wave * 2 + j;
            gload16(Ag + (size_t)(chunk * 16) * K + ks * 32, a_lds[b] + chunk * 512);
            gload16(Bg + (size_t)(chunk * 16) * K + ks * 32, b_lds[b] + chunk * 512);
        }
    };

    STAGE(0, 0);

    for (int ks = 0; ks < NS; ++ks) {
        const int cur = ks & 1;
        asm volatile("s_waitcnt vmcnt(0)" ::: "memory");
        __builtin_amdgcn_s_barrier();
        if (ks + 1 < NS) STAGE(cur ^ 1, ks + 1);

        bf16x8 af[4], bfr[4];
#pragma unroll
        for (int m = 0; m < 4; ++m)
            af[m] = *reinterpret_cast<const bf16x8*>(a_lds[cur] + (wr * 64 + m * 16 + l16) * 32 + g * 8);
#pragma unroll
        for (int n = 0; n < 4; ++n)
            bfr[n] = *reinterpret_cast<const bf16x8*>(b_lds[cur] + (wc * 64 + n * 16 + l16) * 32 + g * 8);
        __builtin_amdgcn_s_setprio(1);
#pragma unroll
        for (int m = 0; m < 4; ++m)
#pragma unroll
            for (int n = 0; n < 4; ++n)
                acc[m][n] = __builtin_amdgcn_mfma_f32_16x16x32_bf16(af[m], bfr[n], acc[m][n], 0, 0, 0);
        __builtin_amdgcn_s_setprio(0);
    }

#pragma unroll
    for (int m = 0; m < 4; ++m)
#pragma unroll
        for (int n = 0; n < 4; ++n)
#pragma unroll
            for (int r = 0; r < 4; ++r) {
                int row = bm * 128 + wr * 64 + m * 16 + g * 4 + r;
                int col = bn * 128 + wc * 64 + n * 16 + l16;
                float v = acc[m][n][r];
                if (EPI == 0) {
                    int part = col >> 10;
                    int hd = col & 1023;
                    int h = hd >> 6, d = hd & 63;
                    outB[(size_t)((part * HEADS + h) * SEQ + row) * HD + d] = f2bf(v);
                } else {
                    outF[(size_t)row * N + col] = v;
                }
            }
}

// ---------------- RoPE in place on Q,K (Q scaled by 1/8 * log2e) ----------------
__global__ __launch_bounds__(256) void rope_kernel(unsigned short* qkv, const int* __restrict__ pos) {
    int idx = blockIdx.x * 256 + threadIdx.x;
    int chunk = idx & 7;
    int row = idx >> 3;
    int s = row & (SEQ - 1);
    int ph = row >> 12;
    float p = (float)pos[s];
    float scale = (ph < HEADS) ? 0.125f * 1.4426950408889634f : 1.0f;
    unsigned short* base = qkv + ((size_t)ph * SEQ + s) * HD + chunk * 8;
    short8 v = *reinterpret_cast<short8*>(base);
    short8 o;
    const float k = -13.287712379549449f / 32.0f;
#pragma unroll
    for (int j = 0; j < 4; ++j) {
        int i = chunk * 4 + j;
        float ang = p * exp2f((float)i * k);
        float sn, cs;
        sincosf(ang, &sn, &cs);
        float x1 = bf2f((unsigned short)v[2 * j]);
        float x2 = bf2f((unsigned short)v[2 * j + 1]);
        o[2 * j]     = (short)f2bf((x1 * cs - x2 * sn) * scale);
        o[2 * j + 1] = (short)f2bf((x1 * sn + x2 * cs) * scale);
    }
    *reinterpret_cast<short8*>(base) = o;
}

// ---------------- V transpose: [s][d] -> VT [h][d][s] ----------------
__global__ __launch_bounds__(256) void transpose_v(const unsigned short* __restrict__ qkv,
                                                   unsigned short* __restrict__ vt) {
    const int st = blockIdx.x;
    const int h = blockIdx.y;
    __shared__ unsigned short tile[64][72];
    const unsigned short* Vg = qkv + (size_t)((2 * HEADS + h) * SEQ) * HD;
    const int tid = threadIdx.x;
#pragma unroll
    for (int j = 0; j < 2; ++j) {
        int b = (tid + j * 256) * 8;
        int row = b >> 6;
        int col = b & 63;
        short8 v = *reinterpret_cast<const short8*>(Vg + (size_t)(st * 64 + row) * HD + col);
#pragma unroll
        for (int i = 0; i < 8; ++i) tile[row][col + i] = (unsigned short)v[i];
    }
    __syncthreads();
#pragma unroll
    for (int j = 0; j < 2; ++j) {
        int b = (tid + j * 256) * 8;
        int d = b >> 6;
        int sc = b & 63;
        short8 o;
#pragma unroll
        for (int i = 0; i < 8; ++i) o[i] = (short)tile[sc + i][d];
        *reinterpret_cast<short8*>(vt + (size_t)(h * HD + d) * SEQ + st * 64 + sc) = o;
    }
}

// ---------------- causal flash attention: 32x32 MFMA, in-register P, split-K LPT ----------------
// 4 waves x 32 q-rows, KVBLK=128 as two 64-halves. R7-verified 32x32 fragment math +
// in-register cvt_pk/shfl_xor(32) P re-frag (no p_lds). 64KB LDS -> 2 blocks/CU.
__global__ __launch_bounds__(256) void attn_kernel(const unsigned short* __restrict__ qkv,
                                                   const unsigned short* __restrict__ vt,
                                                   unsigned short* __restrict__ attnout,
                                                   unsigned short* __restrict__ pO,
                                                   float* __restrict__ lmf) {
    const int bid = blockIdx.x;
    const int xcd = bid & 7;
    const int slot = bid >> 3;                // 0..95
    const int hloc = slot & 1;
    const unsigned char e = TASKS[slot >> 1];
    const int qtile = e & 31;
    const int khalf = (e >> 5) & 1;
    const bool isSplit = (e >> 6) != 0;
    const int T = qtile + 1, Hh = (T + 1) >> 1;
    const int k0 = isSplit ? (khalf ? Hh : 0) : 0;
    const int k1 = isSplit ? (khalf ? T : Hh) : T;
    const int h = xcd * 2 + hloc;

    const int tid = threadIdx.x;
    const int wave = tid >> 6, lane = tid & 63;
    const int l32 = lane & 31, hi = lane >> 5;

    alignas(16) __shared__ unsigned short k_lds[2][128 * 64];   // [kv][d], 128B rows
    alignas(16) __shared__ unsigned short v_lds[2][2][64 * 64]; // [kvhalf][d][kv'], 128B rows

    const unsigned short* Qg = qkv + (size_t)((0 * HEADS + h) * SEQ) * HD;
    const unsigned short* Kg = qkv + (size_t)((1 * HEADS + h) * SEQ) * HD;
    const unsigned short* VTg = vt + (size_t)h * HD * SEQ;

    const int qbase = qtile * 128 + wave * 32;   // wave covers q rows [qbase, qbase+32)
    const int qrow = qbase + l32;

    // Q B-frags (32x32x16): lane holds Q[q=qrow][d = dg*16 + hi*8 .. +7]
    bf16x8 qf[4];
#pragma unroll
    for (int dg = 0; dg < 4; ++dg)
        qf[dg] = *reinterpret_cast<const bf16x8*>(Qg + (size_t)qrow * HD + dg * 16 + hi * 8);

    f32x16 oa[2] = {};            // O^T: C[d][q], d-group dg*32 + (r&3)+8*(r>>2)+4*hi
    float m_r = -1e30f, l_r = 0.f;

    const int rsw = (l32 & 7) << 4;

    // block stages K (16KB) + V (16KB) per tile: 8 gload16 per wave (4 waves)
    auto STAGE = [&](int b, int kt) {
#pragma unroll
        for (int i = 0; i < 4; ++i) {
            int base = wave * 4096 + i * 1024;
            int byte = base + lane * 16;
            int krow = byte >> 7;                       // 0..127
            int kc8 = ((byte >> 4) & 7) ^ (krow & 7);
            gload16(Kg + (size_t)(kt * 128 + krow) * HD + kc8 * 8, (char*)k_lds[b] + base);
            int fr = byte >> 7;                         // 0..127
            int h64 = fr >> 6, vd = fr & 63;
            int vc8 = ((byte >> 4) & 7) ^ (vd & 7);
            gload16(VTg + (size_t)vd * SEQ + kt * 128 + h64 * 64 + vc8 * 8,
                    (char*)v_lds[b] + base);
        }
    };

    STAGE(0, k0);

    for (int kt = k0; kt < k1; ++kt) {
        const int cur = (kt - k0) & 1;
        asm volatile("s_waitcnt vmcnt(0)" ::: "memory");
        __builtin_amdgcn_s_barrier();
        if (kt + 1 < k1) STAGE(cur ^ 1, kt + 1);

#pragma unroll
        for (int hh = 0; hh < 2; ++hh) {
            if (hh && (kt * 128 + 64) > (qbase + 31)) break;   // half B irrelevant

            // S^T = K * Q : s[g][r] = S[q=qrow][kv = kt*128 + hh*64 + g*32 + (r&3)+8*(r>>2)+4*hi]
            f32x16 s[2] = {};
            __builtin_amdgcn_s_setprio(1);
#pragma unroll
            for (int g = 0; g < 2; ++g) {
                int row = hh * 64 + g * 32 + l32;
#pragma unroll
                for (int dg = 0; dg < 4; ++dg) {
                    bf16x8 kf = *reinterpret_cast<const bf16x8*>(
                        (char*)k_lds[cur] + row * 128 + ((dg * 32 + hi * 16) ^ rsw));
                    s[g] = __builtin_amdgcn_mfma_f32_32x32x16_bf16(kf, qf[dg], s[g], 0, 0, 0);
                }
            }
            __builtin_amdgcn_s_setprio(0);

            // causal mask
            if (kt * 128 + hh * 64 + 63 > qbase) {
#pragma unroll
                for (int g = 0; g < 2; ++g)
#pragma unroll
                    for (int r = 0; r < 16; ++r) {
                        int kv = kt * 128 + hh * 64 + g * 32 + (r & 3) + 8 * (r >> 2) + 4 * hi;
                        if (kv > qrow) s[g][r] = -1e30f;
                    }
            }

            // row max: 32 in-lane + 1 shuffle (lanes l and l+32 share q)
            float ma = -1e30f, mb = -1e30f, mc = -1e30f, md = -1e30f;
#pragma unroll
            for (int r = 0; r < 16; r += 4) {
                ma = fmaxf(ma, fmaxf(s[0][r], s[1][r]));
                mb = fmaxf(mb, fmaxf(s[0][r + 1], s[1][r + 1]));
                mc = fmaxf(mc, fmaxf(s[0][r + 2], s[1][r + 2]));
                md = fmaxf(md, fmaxf(s[0][r + 3], s[1][r + 3]));
            }
            float mx = fmaxf(fmaxf(ma, mb), fmaxf(mc, md));
            mx = fmaxf(mx, __shfl_xor(mx, 32));

            // defer-max (log2 domain, THR=8)
            if (__any(mx > m_r + 8.0f)) {
                float mnew = fmaxf(m_r, mx);
                float alpha = __builtin_amdgcn_exp2f(m_r - mnew);
                m_r = mnew;
#pragma unroll
                for (int r = 0; r < 16; ++r) { oa[0][r] *= alpha; oa[1][r] *= alpha; }
                l_r *= alpha;
            }

#pragma unroll
            for (int g = 0; g < 2; ++g)
#pragma unroll
                for (int r = 0; r < 16; ++r) s[g][r] = __builtin_amdgcn_exp2f(s[g][r] - m_r);

            // row sum: 32 in-lane + 1 shuffle
            float ra = 0.f, rb = 0.f;
#pragma unroll
            for (int r = 0; r < 16; r += 2) {
                ra += s[0][r] + s[1][r];
                rb += s[0][r + 1] + s[1][r + 1];
            }
            float rs = ra + rb;
            rs += __shfl_xor(rs, 32);
            l_r += rs;

            // per 32-kv group: in-register P re-frag (R7-verified) + PV
            __builtin_amdgcn_s_setprio(1);
#pragma unroll
            for (int g = 0; g < 2; ++g) {
                u32x4 pfw[2];
#pragma unroll
                for (int u = 0; u < 2; ++u) {
                    unsigned wA = cvt_pk_bf16(s[g][8 * u + 0], s[g][8 * u + 1]);
                    unsigned wC = cvt_pk_bf16(s[g][8 * u + 2], s[g][8 * u + 3]);
                    unsigned wB = cvt_pk_bf16(s[g][8 * u + 4], s[g][8 * u + 5]);
                    unsigned wD = cvt_pk_bf16(s[g][8 * u + 6], s[g][8 * u + 7]);
                    unsigned wAx = __shfl_xor((int)wA, 32), wBx = __shfl_xor((int)wB, 32);
                    unsigned wCx = __shfl_xor((int)wC, 32), wDx = __shfl_xor((int)wD, 32);
                    pfw[u][0] = hi ? wBx : wA;
                    pfw[u][1] = hi ? wDx : wC;
                    pfw[u][2] = hi ? wB : wAx;
                    pfw[u][3] = hi ? wD : wCx;
                }
#pragma unroll
                for (int u = 0; u < 2; ++u) {
                    bf16x8 pf = __builtin_bit_cast(bf16x8, pfw[u]);
                    int ks = g * 2 + u;     // 16-kv slice within this 64 half
#pragma unroll
                    for (int dg = 0; dg < 2; ++dg) {
                        bf16x8 vf = *reinterpret_cast<const bf16x8*>(
                            (char*)v_lds[cur][hh] + (dg * 32 + l32) * 128 + ((ks * 32 + hi * 16) ^ rsw));
                        oa[dg] = __builtin_amdgcn_mfma_f32_32x32x16_bf16(vf, pf, oa[dg], 0, 0, 0);
                    }
                }
            }
            __builtin_amdgcn_s_setprio(0);
        }
    }

    // epilogue: lane holds O[q=qrow][d = dg*32 + (r&3)+8*(r>>2)+4*hi]
    const int ql = wave * 32 + l32;
    if (isSplit) {
        int sidx = (h * 16 + (qtile - 16)) * 2 + khalf;
        unsigned short* Op = pO + (size_t)sidx * 8192;
#pragma unroll
        for (int dg = 0; dg < 2; ++dg)
#pragma unroll
            for (int rq = 0; rq < 4; ++rq) {
                ushort4 ov;
                ov.x = f2bf(oa[dg][4 * rq + 0]);
                ov.y = f2bf(oa[dg][4 * rq + 1]);
                ov.z = f2bf(oa[dg][4 * rq + 2]);
                ov.w = f2bf(oa[dg][4 * rq + 3]);
                *reinterpret_cast<ushort4*>(Op + ql * 64 + dg * 32 + 8 * rq + 4 * hi) = ov;
            }
        if (hi == 0) {
            lmf[sidx * 256 + ql] = l_r;
            lmf[sidx * 256 + 128 + ql] = m_r;
        }
    } else {
        float inv = 1.0f / l_r;
        unsigned short* orow = attnout + (size_t)(qtile * 128 + ql) * DMODEL + h * HD;
#pragma unroll
        for (int dg = 0; dg < 2; ++dg)
#pragma unroll
            for (int rq = 0; rq < 4; ++rq) {
                ushort4 ov;
                ov.x = f2bf(oa[dg][4 * rq + 0] * inv);
                ov.y = f2bf(oa[dg][4 * rq + 1] * inv);
                ov.z = f2bf(oa[dg][4 * rq + 2] * inv);
                ov.w = f2bf(oa[dg][4 * rq + 3] * inv);
                *reinterpret_cast<ushort4*>(orow + dg * 32 + 8 * rq + 4 * hi) = ov;
            }
    }
}

// ---------------- merge K-half partials (qtiles 16..31) ----------------
__global__ __launch_bounds__(256) void merge_kernel(const unsigned short* __restrict__ pO,
                                                    const float* __restrict__ lmf,
                                                    unsigned short* __restrict__ attnout) {
    int idx = blockIdx.x * 256 + threadIdx.x;   // 16 h x 16 qt x 128 q x 8 d8
    if (idx >= 16 * 16 * 1024) return;
    int h = idx / (16 * 1024);
    int r = idx % (16 * 1024);
    int qt = r >> 10;
    int rr = r & 1023;
    int q = rr >> 3, d8 = rr & 7;

    int s0 = (h * 16 + qt) * 2;
    float l0 = lmf[s0 * 256 + q],       m0 = lmf[s0 * 256 + 128 + q];
    float l1 = lmf[(s0 + 1) * 256 + q], m1 = lmf[(s0 + 1) * 256 + 128 + q];
    float m = fmaxf(m0, m1);
    float a0 = __builtin_amdgcn_exp2f(m0 - m), a1 = __builtin_amdgcn_exp2f(m1 - m);
    float L = l0 * a0 + l1 * a1;
    float c0 = a0 / L, c1 = a1 / L;

    const unsigned short* O0 = pO + (size_t)s0 * 8192 + q * 64 + d8 * 8;
    const unsigned short* O1 = O0 + 8192;
    short8 v0 = *reinterpret_cast<const short8*>(O0);
    short8 v1 = *reinterpret_cast<const short8*>(O1);
    short8 o;
#pragma unroll
    for (int j = 0; j < 8; ++j) {
        float val = bf2f((unsigned short)v0[j]) * c0 + bf2f((unsigned short)v1[j]) * c1;
        o[j] = (short)f2bf(val);
    }
    int qtile = qt + 16;
    *reinterpret_cast<short8*>(attnout + (size_t)(qtile * 128 + q) * DMODEL + h * HD + d8 * 8) = o;
}

extern "C" void kernel_launch(void* const* d_in, const int* in_sizes, int n_in,
                              void* d_out, int out_size, void* d_ws, size_t ws_size,
                              hipStream_t stream) {
    const float* x = (const float*)d_in[0];
    const int* pos = (const int*)d_in[1];
    const float* wqkv = (const float*)d_in[2];
    const float* wo = (const float*)d_in[3];
    float* out = (float*)d_out;

    unsigned short* xb = (unsigned short*)d_ws;
    unsigned short* wqkvb = xb + (size_t)SEQ * DMODEL;
    unsigned short* wob = wqkvb + (size_t)NQKV * DMODEL;
    unsigned short* qkvp = wob + (size_t)DMODEL * DMODEL;
    unsigned short* vt = qkvp + (size_t)3 * HEADS * SEQ * HD;
    unsigned short* attnb = vt + (size_t)HEADS * HD * SEQ;

    // split-K scratch lives in xb/wqkvb (dead after gemm1): lmf 512KB, pO 8MB
    char* sbase = (char*)d_ws;
    float* lmf = (float*)sbase;
    unsigned short* pO = (unsigned short*)(sbase + (1 << 20));

    f2bf_all<<<2048, 256, 0, stream>>>(x, wqkv, wo, xb);

    dim3 g1(SEQ / 128, NQKV / 128);
    gemm_bt<0><<<g1, 256, 0, stream>>>(xb, wqkvb, nullptr, qkvp, SEQ, NQKV, DMODEL);

    rope_kernel<<<(2 * HEADS * SEQ * 8) / 256, 256, 0, stream>>>(qkvp, pos);
    transpose_v<<<dim3(SEQ / 64, HEADS), 256, 0, stream>>>(qkvp, vt);

    attn_kernel<<<768, 256, 0, stream>>>(qkvp, vt, attnb, pO, lmf);
    merge_kernel<<<(16 * 16 * 1024 + 255) / 256, 256, 0, stream>>>(pO, lmf, attnb);

    dim3 g2(SEQ / 128, DMODEL / 128);
    gemm_bt<1><<<g2, 256, 0, stream>>>(attnb, wob, out, nullptr, SEQ, DMODEL, DMODEL);
}

// Round 18
// 147.165 us; speedup vs baseline: 1.0739x; 1.0739x over previous
//
#include <hip/hip_runtime.h>

#define SEQ 4096
#define DMODEL 1024
#define HEADS 16
#define HD 64
#define NQKV 3072

typedef __attribute__((ext_vector_type(8))) __bf16 bf16x8;
typedef __attribute__((ext_vector_type(4))) __bf16 bf16x4;
typedef __attribute__((ext_vector_type(8))) short short8;
typedef __attribute__((ext_vector_type(4))) float f32x4;
typedef __attribute__((ext_vector_type(16))) float f32x16;
typedef __attribute__((ext_vector_type(4))) unsigned int u32x4;

__device__ __forceinline__ unsigned short f2bf(float f) {
    unsigned u = __builtin_bit_cast(unsigned, f);
    return (unsigned short)((u + 0x7fffu + ((u >> 16) & 1u)) >> 16);
}
__device__ __forceinline__ float bf2f(unsigned short h) {
    return __builtin_bit_cast(float, (unsigned)h << 16);
}
__device__ __forceinline__ unsigned cvt_pk_bf16(float lo, float hi) {
    unsigned r;
    asm("v_cvt_pk_bf16_f32 %0, %1, %2" : "=v"(r) : "v"(lo), "v"(hi));
    return r;
}

__device__ __forceinline__ void gload16(const void* g, void* l) {
    __builtin_amdgcn_global_load_lds(
        (const __attribute__((address_space(1))) unsigned int*)g,
        (__attribute__((address_space(3))) unsigned int*)l, 16, 0, 0);
}

// per-head task table, LPT (length-desc). bit6=split, bit5=khalf, bits0-4=qtile(256-row)
#define TS(qt, kh) (0x40 | ((kh) << 5) | (qt))
__device__ __constant__ unsigned char TASKS[28] = {
    TS(15,0), TS(15,1), TS(14,0), TS(14,1), TS(13,0), TS(13,1),
    TS(12,0), TS(12,1), TS(11,0), TS(11,1), TS(10,0), TS(10,1),
    TS(9,0),  TS(9,1),  TS(8,0),  TS(8,1),  TS(7,0),  TS(7,1),
    3,        TS(6,0),  TS(6,1),  2,        TS(5,0),  TS(5,1),
    TS(4,0),  TS(4,1),  1,        0
};

// ---------------- fp32 -> bf16 convert, all three tensors in one launch ----------------
__global__ void f2bf_all(const float* __restrict__ x, const float* __restrict__ wqkv,
                         const float* __restrict__ wo, unsigned short* __restrict__ dst) {
    const int N0 = SEQ * DMODEL / 4;
    const int N1 = N0 + NQKV * DMODEL / 4;
    const int NT = N1 + DMODEL * DMODEL / 4;
    int i = blockIdx.x * 256 + threadIdx.x;
    int stride = gridDim.x * 256;
    for (; i < NT; i += stride) {
        const float4* src;
        if (i < N0)      src = reinterpret_cast<const float4*>(x) + i;
        else if (i < N1) src = reinterpret_cast<const float4*>(wqkv) + (i - N0);
        else             src = reinterpret_cast<const float4*>(wo) + (i - N1);
        float4 f = *src;
        ushort4 o;
        o.x = f2bf(f.x); o.y = f2bf(f.y); o.z = f2bf(f.z); o.w = f2bf(f.w);
        reinterpret_cast<ushort4*>(dst)[i] = o;
    }
}

// ---------------- bf16 GEMM, C = A(MxK) * B(NxK)^T ----------------
template <int EPI>
__global__ __launch_bounds__(256) void gemm_bt(const unsigned short* __restrict__ A,
                                               const unsigned short* __restrict__ B,
                                               float* __restrict__ outF,
                                               unsigned short* __restrict__ outB,
                                               int M, int N, int K) {
    alignas(16) __shared__ unsigned short a_lds[2][128 * 32];
    alignas(16) __shared__ unsigned short b_lds[2][128 * 32];
    const int tid = threadIdx.x;
    const int wave = tid >> 6, lane = tid & 63;
    const int l16 = lane & 15, g = lane >> 4;
    const int wr = wave >> 1, wc = wave & 1;
    const int bm = blockIdx.x, bn = blockIdx.y;

    const int lrow = lane >> 2;
    const int lcol = (lane & 3) * 8;

    const unsigned short* Ag = A + (size_t)(bm * 128 + lrow) * K + lcol;
    const unsigned short* Bg = B + (size_t)(bn * 128 + lrow) * K + lcol;

    f32x4 acc[4][4] = {};
    const int NS = K / 32;

    auto STAGE = [&](int b, int ks) {
#pragma unroll
        for (int j = 0; j < 2; ++j) {
            int chunk = wave * 2 + j;
            gload16(Ag + (size_t)(chunk * 16) * K + ks * 32, a_lds[b] + chunk * 512);
            gload16(Bg + (size_t)(chunk * 16) * K + ks * 32, b_lds[b] + chunk * 512);
        }
    };

    STAGE(0, 0);

    for (int ks = 0; ks < NS; ++ks) {
        const int cur = ks & 1;
        asm volatile("s_waitcnt vmcnt(0)" ::: "memory");
        __builtin_amdgcn_s_barrier();
        if (ks + 1 < NS) STAGE(cur ^ 1, ks + 1);

        bf16x8 af[4], bfr[4];
#pragma unroll
        for (int m = 0; m < 4; ++m)
            af[m] = *reinterpret_cast<const bf16x8*>(a_lds[cur] + (wr * 64 + m * 16 + l16) * 32 + g * 8);
#pragma unroll
        for (int n = 0; n < 4; ++n)
            bfr[n] = *reinterpret_cast<const bf16x8*>(b_lds[cur] + (wc * 64 + n * 16 + l16) * 32 + g * 8);
        __builtin_amdgcn_s_setprio(1);
#pragma unroll
        for (int m = 0; m < 4; ++m)
#pragma unroll
            for (int n = 0; n < 4; ++n)
                acc[m][n] = __builtin_amdgcn_mfma_f32_16x16x32_bf16(af[m], bfr[n], acc[m][n], 0, 0, 0);
        __builtin_amdgcn_s_setprio(0);
    }

#pragma unroll
    for (int m = 0; m < 4; ++m)
#pragma unroll
        for (int n = 0; n < 4; ++n)
#pragma unroll
            for (int r = 0; r < 4; ++r) {
                int row = bm * 128 + wr * 64 + m * 16 + g * 4 + r;
                int col = bn * 128 + wc * 64 + n * 16 + l16;
                float v = acc[m][n][r];
                if (EPI == 0) {
                    int part = col >> 10;
                    int hd = col & 1023;
                    int h = hd >> 6, d = hd & 63;
                    outB[(size_t)((part * HEADS + h) * SEQ + row) * HD + d] = f2bf(v);
                } else {
                    outF[(size_t)row * N + col] = v;
                }
            }
}

// ---------------- RoPE in place on Q,K (Q scaled by 1/8 * log2e) ----------------
__global__ __launch_bounds__(256) void rope_kernel(unsigned short* qkv, const int* __restrict__ pos) {
    int idx = blockIdx.x * 256 + threadIdx.x;
    int chunk = idx & 7;
    int row = idx >> 3;
    int s = row & (SEQ - 1);
    int ph = row >> 12;
    float p = (float)pos[s];
    float scale = (ph < HEADS) ? 0.125f * 1.4426950408889634f : 1.0f;
    unsigned short* base = qkv + ((size_t)ph * SEQ + s) * HD + chunk * 8;
    short8 v = *reinterpret_cast<short8*>(base);
    short8 o;
    const float k = -13.287712379549449f / 32.0f;
#pragma unroll
    for (int j = 0; j < 4; ++j) {
        int i = chunk * 4 + j;
        float ang = p * exp2f((float)i * k);
        float sn, cs;
        sincosf(ang, &sn, &cs);
        float x1 = bf2f((unsigned short)v[2 * j]);
        float x2 = bf2f((unsigned short)v[2 * j + 1]);
        o[2 * j]     = (short)f2bf((x1 * cs - x2 * sn) * scale);
        o[2 * j + 1] = (short)f2bf((x1 * sn + x2 * cs) * scale);
    }
    *reinterpret_cast<short8*>(base) = o;
}

// ---------------- V transpose: [s][d] -> VT [h][d][s] ----------------
__global__ __launch_bounds__(256) void transpose_v(const unsigned short* __restrict__ qkv,
                                                   unsigned short* __restrict__ vt) {
    const int st = blockIdx.x;
    const int h = blockIdx.y;
    __shared__ unsigned short tile[64][72];
    const unsigned short* Vg = qkv + (size_t)((2 * HEADS + h) * SEQ) * HD;
    const int tid = threadIdx.x;
#pragma unroll
    for (int j = 0; j < 2; ++j) {
        int b = (tid + j * 256) * 8;
        int row = b >> 6;
        int col = b & 63;
        short8 v = *reinterpret_cast<const short8*>(Vg + (size_t)(st * 64 + row) * HD + col);
#pragma unroll
        for (int i = 0; i < 8; ++i) tile[row][col + i] = (unsigned short)v[i];
    }
    __syncthreads();
#pragma unroll
    for (int j = 0; j < 2; ++j) {
        int b = (tid + j * 256) * 8;
        int d = b >> 6;
        int sc = b & 63;
        short8 o;
#pragma unroll
        for (int i = 0; i < 8; ++i) o[i] = (short)tile[sc + i][d];
        *reinterpret_cast<short8*>(vt + (size_t)(h * HD + d) * SEQ + st * 64 + sc) = o;
    }
}

// ---------------- causal flash attention ----------------
// 8 waves x 32 q-rows (QBLK=256), 32x32 MFMA, in-register P re-frag (no p_lds),
// KVBLK=128 as two 64-halves, 64KB LDS -> 2 blocks/CU (16 waves/CU),
// per-XCD atomic LPT queue + split-K for qtiles >= 4.
__global__ __launch_bounds__(512) void attn_kernel(const unsigned short* __restrict__ qkv,
                                                   const unsigned short* __restrict__ vt,
                                                   unsigned short* __restrict__ attnout,
                                                   int* __restrict__ qcnt,
                                                   unsigned short* __restrict__ pO,
                                                   float* __restrict__ lmf) {
    const int xcd = blockIdx.x & 7;
    const int tid = threadIdx.x;
    const int wave = tid >> 6, lane = tid & 63;
    const int l32 = lane & 31, hi = lane >> 5;

    alignas(16) __shared__ unsigned short k_lds[2][128 * 64];   // [kv][d], 128B rows
    alignas(16) __shared__ unsigned short v_lds[2][2][64 * 64]; // [kvhalf][d][kv'], 128B rows
    __shared__ int slot_sh;

    const int rsw = (l32 & 7) << 4;

    for (;;) {
        if (tid == 0) slot_sh = atomicAdd(&qcnt[xcd], 1);
        __syncthreads();
        const int t = slot_sh;
        __syncthreads();
        if (t >= 56) break;

        const int hloc = t & 1;
        const unsigned char e = TASKS[t >> 1];
        const int qtile = e & 31;
        const int khalf = (e >> 5) & 1;
        const bool isSplit = (e >> 6) != 0;
        const int T = 2 * qtile + 2, Hh = qtile + 1;
        const int k0 = isSplit ? (khalf ? Hh : 0) : 0;
        const int k1 = isSplit ? (khalf ? T : Hh) : T;
        const int h = xcd * 2 + hloc;

        const unsigned short* Qg = qkv + (size_t)((0 * HEADS + h) * SEQ) * HD;
        const unsigned short* Kg = qkv + (size_t)((1 * HEADS + h) * SEQ) * HD;
        const unsigned short* VTg = vt + (size_t)h * HD * SEQ;

        const int qbase = qtile * 256 + wave * 32;   // wave covers [qbase, qbase+32)
        const int qrow = qbase + l32;

        // Q B-frags (32x32x16): lane holds Q[q=qrow][d = dg*16 + hi*8 .. +7]
        bf16x8 qf[4];
#pragma unroll
        for (int dg = 0; dg < 4; ++dg)
            qf[dg] = *reinterpret_cast<const bf16x8*>(Qg + (size_t)qrow * HD + dg * 16 + hi * 8);

        f32x16 oa[2] = {};
        float m_r = -1e30f, l_r = 0.f;

        // block stages K (16KB) + V (16KB) per tile: 4 gload16 per wave (8 waves)
        auto STAGE = [&](int b, int kt) {
#pragma unroll
            for (int i = 0; i < 2; ++i) {
                int base = wave * 2048 + i * 1024;
                int byte = base + lane * 16;
                int krow = byte >> 7;                       // 0..127
                int kc8 = ((byte >> 4) & 7) ^ (krow & 7);
                gload16(Kg + (size_t)(kt * 128 + krow) * HD + kc8 * 8, (char*)k_lds[b] + base);
                int fr = byte >> 7;                         // 0..127
                int h64 = fr >> 6, vd = fr & 63;
                int vc8 = ((byte >> 4) & 7) ^ (vd & 7);
                gload16(VTg + (size_t)vd * SEQ + kt * 128 + h64 * 64 + vc8 * 8,
                        (char*)v_lds[b] + base);
            }
        };

        STAGE(0, k0);

        for (int kt = k0; kt < k1; ++kt) {
            const int cur = (kt - k0) & 1;
            asm volatile("s_waitcnt vmcnt(0)" ::: "memory");
            __builtin_amdgcn_s_barrier();
            if (kt + 1 < k1) STAGE(cur ^ 1, kt + 1);

#pragma unroll
            for (int hh = 0; hh < 2; ++hh) {
                if (hh && (kt * 128 + 64) > (qbase + 31)) break;

                // S^T = K*Q : s[g][r] = S[q=qrow][kv = kt*128+hh*64+g*32+(r&3)+8*(r>>2)+4*hi]
                f32x16 s[2] = {};
                __builtin_amdgcn_s_setprio(1);
#pragma unroll
                for (int g = 0; g < 2; ++g) {
                    int row = hh * 64 + g * 32 + l32;
#pragma unroll
                    for (int dg = 0; dg < 4; ++dg) {
                        bf16x8 kf = *reinterpret_cast<const bf16x8*>(
                            (char*)k_lds[cur] + row * 128 + ((dg * 32 + hi * 16) ^ rsw));
                        s[g] = __builtin_amdgcn_mfma_f32_32x32x16_bf16(kf, qf[dg], s[g], 0, 0, 0);
                    }
                }
                __builtin_amdgcn_s_setprio(0);

                if (kt * 128 + hh * 64 + 63 > qbase) {
#pragma unroll
                    for (int g = 0; g < 2; ++g)
#pragma unroll
                        for (int r = 0; r < 16; ++r) {
                            int kv = kt * 128 + hh * 64 + g * 32 + (r & 3) + 8 * (r >> 2) + 4 * hi;
                            if (kv > qrow) s[g][r] = -1e30f;
                        }
                }

                // row max: 32 in-lane + 1 shuffle
                float ma = -1e30f, mb = -1e30f, mc = -1e30f, md = -1e30f;
#pragma unroll
                for (int r = 0; r < 16; r += 4) {
                    ma = fmaxf(ma, fmaxf(s[0][r], s[1][r]));
                    mb = fmaxf(mb, fmaxf(s[0][r + 1], s[1][r + 1]));
                    mc = fmaxf(mc, fmaxf(s[0][r + 2], s[1][r + 2]));
                    md = fmaxf(md, fmaxf(s[0][r + 3], s[1][r + 3]));
                }
                float mx = fmaxf(fmaxf(ma, mb), fmaxf(mc, md));
                mx = fmaxf(mx, __shfl_xor(mx, 32));

                if (__any(mx > m_r + 8.0f)) {
                    float mnew = fmaxf(m_r, mx);
                    float alpha = __builtin_amdgcn_exp2f(m_r - mnew);
                    m_r = mnew;
#pragma unroll
                    for (int r = 0; r < 16; ++r) { oa[0][r] *= alpha; oa[1][r] *= alpha; }
                    l_r *= alpha;
                }

#pragma unroll
                for (int g = 0; g < 2; ++g)
#pragma unroll
                    for (int r = 0; r < 16; ++r) s[g][r] = __builtin_amdgcn_exp2f(s[g][r] - m_r);

                float ra = 0.f, rb = 0.f;
#pragma unroll
                for (int r = 0; r < 16; r += 2) {
                    ra += s[0][r] + s[1][r];
                    rb += s[0][r + 1] + s[1][r + 1];
                }
                float rs = ra + rb;
                rs += __shfl_xor(rs, 32);
                l_r += rs;

                // in-register P re-frag (R7-verified) + PV
                __builtin_amdgcn_s_setprio(1);
#pragma unroll
                for (int g = 0; g < 2; ++g) {
                    u32x4 pfw[2];
#pragma unroll
                    for (int u = 0; u < 2; ++u) {
                        unsigned wA = cvt_pk_bf16(s[g][8 * u + 0], s[g][8 * u + 1]);
                        unsigned wC = cvt_pk_bf16(s[g][8 * u + 2], s[g][8 * u + 3]);
                        unsigned wB = cvt_pk_bf16(s[g][8 * u + 4], s[g][8 * u + 5]);
                        unsigned wD = cvt_pk_bf16(s[g][8 * u + 6], s[g][8 * u + 7]);
                        unsigned wAx = __shfl_xor((int)wA, 32), wBx = __shfl_xor((int)wB, 32);
                        unsigned wCx = __shfl_xor((int)wC, 32), wDx = __shfl_xor((int)wD, 32);
                        pfw[u][0] = hi ? wBx : wA;
                        pfw[u][1] = hi ? wDx : wC;
                        pfw[u][2] = hi ? wB : wAx;
                        pfw[u][3] = hi ? wD : wCx;
                    }
#pragma unroll
                    for (int u = 0; u < 2; ++u) {
                        bf16x8 pf = __builtin_bit_cast(bf16x8, pfw[u]);
                        int ks = g * 2 + u;
#pragma unroll
                        for (int dg = 0; dg < 2; ++dg) {
                            bf16x8 vf = *reinterpret_cast<const bf16x8*>(
                                (char*)v_lds[cur][hh] + (dg * 32 + l32) * 128 + ((ks * 32 + hi * 16) ^ rsw));
                            oa[dg] = __builtin_amdgcn_mfma_f32_32x32x16_bf16(vf, pf, oa[dg], 0, 0, 0);
                        }
                    }
                }
                __builtin_amdgcn_s_setprio(0);
            }
        }

        // epilogue: lane holds O[q=qrow][d = dg*32 + (r&3)+8*(r>>2)+4*hi]
        const int ql = wave * 32 + l32;
        if (isSplit) {
            int sidx = (h * 12 + (qtile - 4)) * 2 + khalf;
            unsigned short* Op = pO + (size_t)sidx * 16384;
#pragma unroll
            for (int dg = 0; dg < 2; ++dg)
#pragma unroll
                for (int rq = 0; rq < 4; ++rq) {
                    ushort4 ov;
                    ov.x = f2bf(oa[dg][4 * rq + 0]);
                    ov.y = f2bf(oa[dg][4 * rq + 1]);
                    ov.z = f2bf(oa[dg][4 * rq + 2]);
                    ov.w = f2bf(oa[dg][4 * rq + 3]);
                    *reinterpret_cast<ushort4*>(Op + ql * 64 + dg * 32 + 8 * rq + 4 * hi) = ov;
                }
            if (hi == 0) {
                lmf[sidx * 512 + ql] = l_r;
                lmf[sidx * 512 + 256 + ql] = m_r;
            }
        } else {
            float inv = 1.0f / l_r;
            unsigned short* orow = attnout + (size_t)(qtile * 256 + ql) * DMODEL + h * HD;
#pragma unroll
            for (int dg = 0; dg < 2; ++dg)
#pragma unroll
                for (int rq = 0; rq < 4; ++rq) {
                    ushort4 ov;
                    ov.x = f2bf(oa[dg][4 * rq + 0] * inv);
                    ov.y = f2bf(oa[dg][4 * rq + 1] * inv);
                    ov.z = f2bf(oa[dg][4 * rq + 2] * inv);
                    ov.w = f2bf(oa[dg][4 * rq + 3] * inv);
                    *reinterpret_cast<ushort4*>(orow + dg * 32 + 8 * rq + 4 * hi) = ov;
                }
        }
    }
}

// ---------------- merge K-half partials (qtiles 4..15, 256-row) ----------------
__global__ __launch_bounds__(256) void merge_kernel(const unsigned short* __restrict__ pO,
                                                    const float* __restrict__ lmf,
                                                    unsigned short* __restrict__ attnout) {
    int idx = blockIdx.x * 256 + threadIdx.x;   // 16 h x 12 qt x 256 q x 8 d8
    if (idx >= 16 * 12 * 2048) return;
    int h = idx / (12 * 2048);
    int r = idx % (12 * 2048);
    int qt = r >> 11;
    int rr = r & 2047;
    int q = rr >> 3, d8 = rr & 7;

    int s0 = (h * 12 + qt) * 2;
    float l0 = lmf[s0 * 512 + q],       m0 = lmf[s0 * 512 + 256 + q];
    float l1 = lmf[(s0 + 1) * 512 + q], m1 = lmf[(s0 + 1) * 512 + 256 + q];
    float m = fmaxf(m0, m1);
    float a0 = __builtin_amdgcn_exp2f(m0 - m), a1 = __builtin_amdgcn_exp2f(m1 - m);
    float L = l0 * a0 + l1 * a1;
    float c0 = a0 / L, c1 = a1 / L;

    const unsigned short* O0 = pO + (size_t)s0 * 16384 + q * 64 + d8 * 8;
    const unsigned short* O1 = O0 + 16384;
    short8 v0 = *reinterpret_cast<const short8*>(O0);
    short8 v1 = *reinterpret_cast<const short8*>(O1);
    short8 o;
#pragma unroll
    for (int j = 0; j < 8; ++j) {
        float val = bf2f((unsigned short)v0[j]) * c0 + bf2f((unsigned short)v1[j]) * c1;
        o[j] = (short)f2bf(val);
    }
    int qtile = qt + 4;
    *reinterpret_cast<short8*>(attnout + (size_t)(qtile * 256 + q) * DMODEL + h * HD + d8 * 8) = o;
}

extern "C" void kernel_launch(void* const* d_in, const int* in_sizes, int n_in,
                              void* d_out, int out_size, void* d_ws, size_t ws_size,
                              hipStream_t stream) {
    const float* x = (const float*)d_in[0];
    const int* pos = (const int*)d_in[1];
    const float* wqkv = (const float*)d_in[2];
    const float* wo = (const float*)d_in[3];
    float* out = (float*)d_out;

    unsigned short* xb = (unsigned short*)d_ws;
    unsigned short* wqkvb = xb + (size_t)SEQ * DMODEL;
    unsigned short* wob = wqkvb + (size_t)NQKV * DMODEL;
    unsigned short* qkvp = wob + (size_t)DMODEL * DMODEL;
    unsigned short* vt = qkvp + (size_t)3 * HEADS * SEQ * HD;
    unsigned short* attnb = vt + (size_t)HEADS * HD * SEQ;

    // scratch in xb/wqkvb (dead after gemm1): qcnt 64B | lmf 768KB | pO 12MB
    char* sbase = (char*)d_ws;
    int* qcnt = (int*)sbase;
    float* lmf = (float*)(sbase + 1024);
    unsigned short* pO = (unsigned short*)(sbase + (1 << 20));

    f2bf_all<<<2048, 256, 0, stream>>>(x, wqkv, wo, xb);

    dim3 g1(SEQ / 128, NQKV / 128);
    gemm_bt<0><<<g1, 256, 0, stream>>>(xb, wqkvb, nullptr, qkvp, SEQ, NQKV, DMODEL);

    rope_kernel<<<(2 * HEADS * SEQ * 8) / 256, 256, 0, stream>>>(qkvp, pos);
    transpose_v<<<dim3(SEQ / 64, HEADS), 256, 0, stream>>>(qkvp, vt);

    hipMemsetAsync(qcnt, 0, 64, stream);
    attn_kernel<<<512, 512, 0, stream>>>(qkvp, vt, attnb, qcnt, pO, lmf);
    merge_kernel<<<(16 * 12 * 2048 + 255) / 256, 256, 0, stream>>>(pO, lmf, attnb);

    dim3 g2(SEQ / 128, DMODEL / 128);
    gemm_bt<1><<<g2, 256, 0, stream>>>(attnb, wob, out, nullptr, SEQ, DMODEL, DMODEL);
}

// Round 20
// 137.577 us; speedup vs baseline: 1.1488x; 1.0697x over previous
//
#include <hip/hip_runtime.h>

#define SEQ 4096
#define DMODEL 1024
#define HEADS 16
#define HD 64
#define NQKV 3072

typedef __attribute__((ext_vector_type(8))) __bf16 bf16x8;
typedef __attribute__((ext_vector_type(4))) __bf16 bf16x4;
typedef __attribute__((ext_vector_type(8))) short short8;
typedef __attribute__((ext_vector_type(4))) float f32x4;
typedef __attribute__((ext_vector_type(16))) float f32x16;
typedef __attribute__((ext_vector_type(4))) unsigned int u32x4;

__device__ __forceinline__ unsigned short f2bf(float f) {
    unsigned u = __builtin_bit_cast(unsigned, f);
    return (unsigned short)((u + 0x7fffu + ((u >> 16) & 1u)) >> 16);
}
__device__ __forceinline__ float bf2f(unsigned short h) {
    return __builtin_bit_cast(float, (unsigned)h << 16);
}
__device__ __forceinline__ unsigned cvt_pk_bf16(float lo, float hi) {
    unsigned r;
    asm("v_cvt_pk_bf16_f32 %0, %1, %2" : "=v"(r) : "v"(lo), "v"(hi));
    return r;
}

__device__ __forceinline__ void gload16(const void* g, void* l) {
    __builtin_amdgcn_global_load_lds(
        (const __attribute__((address_space(1))) unsigned int*)g,
        (__attribute__((address_space(3))) unsigned int*)l, 16, 0, 0);
}

// per-head task table, LPT (length-desc). bit6=split, bit5=khalf, bits0-4=qtile(256-row)
#define TS(qt, kh) (0x40 | ((kh) << 5) | (qt))
__device__ __constant__ unsigned char TASKS[28] = {
    TS(15,0), TS(15,1), TS(14,0), TS(14,1), TS(13,0), TS(13,1),
    TS(12,0), TS(12,1), TS(11,0), TS(11,1), TS(10,0), TS(10,1),
    TS(9,0),  TS(9,1),  TS(8,0),  TS(8,1),  TS(7,0),  TS(7,1),
    3,        TS(6,0),  TS(6,1),  2,        TS(5,0),  TS(5,1),
    TS(4,0),  TS(4,1),  1,        0
};

// ---------------- fp32 -> bf16 convert + RoPE cos/sin table gen ----------------
__global__ void f2bf_all(const float* __restrict__ x, const float* __restrict__ wqkv,
                         const float* __restrict__ wo, const int* __restrict__ pos,
                         unsigned short* __restrict__ dst,
                         float* __restrict__ csT, float* __restrict__ snT) {
    const int N0 = SEQ * DMODEL / 4;
    const int N1 = N0 + NQKV * DMODEL / 4;
    const int NT = N1 + DMODEL * DMODEL / 4;
    int i = blockIdx.x * 256 + threadIdx.x;
    int stride = gridDim.x * 256;
    for (; i < NT; i += stride) {
        const float4* src;
        if (i < N0)      src = reinterpret_cast<const float4*>(x) + i;
        else if (i < N1) src = reinterpret_cast<const float4*>(wqkv) + (i - N0);
        else             src = reinterpret_cast<const float4*>(wo) + (i - N1);
        float4 f = *src;
        ushort4 o;
        o.x = f2bf(f.x); o.y = f2bf(f.y); o.z = f2bf(f.z); o.w = f2bf(f.w);
        reinterpret_cast<ushort4*>(dst)[i] = o;
    }
    const float kk = -13.287712379549449f / 32.0f;  // -log2(10000)/32
    for (int idx = blockIdx.x * 256 + threadIdx.x; idx < SEQ * 32; idx += stride) {
        int s = idx >> 5, fi = idx & 31;
        float p = (float)pos[s];
        float ang = p * exp2f((float)fi * kk);
        float sn_, cs_;
        sincosf(ang, &sn_, &cs_);
        csT[idx] = cs_;
        snT[idx] = sn_;
    }
}

// ---------------- bf16 GEMM, C = A(MxK) * B(NxK)^T ----------------
// EPI 0: fused epilogue -> roped Q/K into qkv pack [part][h][s][64] + V^T into vtp [h][d][s]
// EPI 1: fp32 row-major to outF
template <int EPI>
__global__ __launch_bounds__(256) void gemm_bt(const unsigned short* __restrict__ A,
                                               const unsigned short* __restrict__ B,
                                               float* __restrict__ outF,
                                               unsigned short* __restrict__ outB,
                                               unsigned short* __restrict__ vtp,
                                               const float* __restrict__ csT,
                                               const float* __restrict__ snT,
                                               int M, int N, int K) {
    alignas(16) __shared__ unsigned short a_lds[2][128 * 32];
    alignas(16) __shared__ unsigned short b_lds[2][128 * 32];
    __shared__ unsigned short vtile[4][16][72];   // per-wave V-transpose bounce
    const int tid = threadIdx.x;
    const int wave = tid >> 6, lane = tid & 63;
    const int l16 = lane & 15, g = lane >> 4;
    const int wr = wave >> 1, wc = wave & 1;
    const int bm = blockIdx.x, bn = blockIdx.y;

    const int lrow = lane >> 2;
    const int lcol = (lane & 3) * 8;

    const unsigned short* Ag = A + (size_t)(bm * 128 + lrow) * K + lcol;
    const unsigned short* Bg = B + (size_t)(bn * 128 + lrow) * K + lcol;

    f32x4 acc[4][4] = {};
    const int NS = K / 32;

    auto STAGE = [&](int b, int ks) {
#pragma unroll
        for (int j = 0; j < 2; ++j) {
            int chunk = wave * 2 + j;
            gload16(Ag + (size_t)(chunk * 16) * K + ks * 32, a_lds[b] + chunk * 512);
            gload16(Bg + (size_t)(chunk * 16) * K + ks * 32, b_lds[b] + chunk * 512);
        }
    };

    STAGE(0, 0);

    for (int ks = 0; ks < NS; ++ks) {
        const int cur = ks & 1;
        asm volatile("s_waitcnt vmcnt(0)" ::: "memory");
        __builtin_amdgcn_s_barrier();
        if (ks + 1 < NS) STAGE(cur ^ 1, ks + 1);

        bf16x8 af[4], bfr[4];
#pragma unroll
        for (int m = 0; m < 4; ++m)
            af[m] = *reinterpret_cast<const bf16x8*>(a_lds[cur] + (wr * 64 + m * 16 + l16) * 32 + g * 8);
#pragma unroll
        for (int n = 0; n < 4; ++n)
            bfr[n] = *reinterpret_cast<const bf16x8*>(b_lds[cur] + (wc * 64 + n * 16 + l16) * 32 + g * 8);
        __builtin_amdgcn_s_setprio(1);
#pragma unroll
        for (int m = 0; m < 4; ++m)
#pragma unroll
            for (int n = 0; n < 4; ++n)
                acc[m][n] = __builtin_amdgcn_mfma_f32_16x16x32_bf16(af[m], bfr[n], acc[m][n], 0, 0, 0);
        __builtin_amdgcn_s_setprio(0);
    }

    if (EPI == 0) {
        const float QS = 0.125f * 1.4426950408889634f;  // softmax scale * log2e
#pragma unroll
        for (int n = 0; n < 4; ++n) {
            const int col = bn * 128 + wc * 64 + n * 16 + l16;
            const int part = col >> 10;
            const int hh = (col >> 6) & 15;
            const int d = n * 16 + l16;       // 0..63 within head (since HD=64, col%64 == (n*16+l16)%64; col chunks are 16-wide within one head)
            if (part < 2) {
                // fused RoPE: partner element lives in lane^1
                const int fi = (col & 63) >> 1;
                const float sc = (part == 0) ? QS : 1.0f;
                const bool odd = (col & 1) != 0;
#pragma unroll
                for (int m = 0; m < 4; ++m)
#pragma unroll
                    for (int r = 0; r < 4; ++r) {
                        int row = bm * 128 + wr * 64 + m * 16 + g * 4 + r;
                        float v = acc[m][n][r];
                        float pp = __shfl_xor(v, 1);
                        float cs_ = csT[row * 32 + fi];
                        float sn_ = snT[row * 32 + fi];
                        float out = odd ? (pp * sn_ + v * cs_) : (v * cs_ - pp * sn_);
                        outB[(size_t)((part * HEADS + hh) * SEQ + row) * HD + (col & 63)] = f2bf(out * sc);
                    }
            } else {
                // V: transpose via per-wave LDS tile [16 d][64 s] -> coalesced [h][d][s]
#pragma unroll
                for (int m = 0; m < 4; ++m)
#pragma unroll
                    for (int r = 0; r < 4; ++r)
                        vtile[wave][l16][m * 16 + g * 4 + r] = f2bf(acc[m][n][r]);
#pragma unroll
                for (int dd = 0; dd < 16; ++dd) {
                    int dg = ((col & 63) & ~15) + dd;   // 16-wide d-chunk this n covers
                    vtp[(size_t)(hh * HD + dg) * SEQ + bm * 128 + wr * 64 + lane] =
                        vtile[wave][dd][lane];
                }
            }
        }
    } else {
#pragma unroll
        for (int m = 0; m < 4; ++m)
#pragma unroll
            for (int n = 0; n < 4; ++n)
#pragma unroll
                for (int r = 0; r < 4; ++r) {
                    int row = bm * 128 + wr * 64 + m * 16 + g * 4 + r;
                    int col = bn * 128 + wc * 64 + n * 16 + l16;
                    outF[(size_t)row * N + col] = acc[m][n][r];
                }
    }
}

// ---------------- causal flash attention (R18, unchanged) ----------------
__global__ __launch_bounds__(512) void attn_kernel(const unsigned short* __restrict__ qkv,
                                                   const unsigned short* __restrict__ vt,
                                                   unsigned short* __restrict__ attnout,
                                                   int* __restrict__ qcnt,
                                                   unsigned short* __restrict__ pO,
                                                   float* __restrict__ lmf) {
    const int xcd = blockIdx.x & 7;
    const int tid = threadIdx.x;
    const int wave = tid >> 6, lane = tid & 63;
    const int l32 = lane & 31, hi = lane >> 5;

    alignas(16) __shared__ unsigned short k_lds[2][128 * 64];
    alignas(16) __shared__ unsigned short v_lds[2][2][64 * 64];
    __shared__ int slot_sh;

    const int rsw = (l32 & 7) << 4;

    for (;;) {
        if (tid == 0) slot_sh = atomicAdd(&qcnt[xcd], 1);
        __syncthreads();
        const int t = slot_sh;
        __syncthreads();
        if (t >= 56) break;

        const int hloc = t & 1;
        const unsigned char e = TASKS[t >> 1];
        const int qtile = e & 31;
        const int khalf = (e >> 5) & 1;
        const bool isSplit = (e >> 6) != 0;
        const int T = 2 * qtile + 2, Hh = qtile + 1;
        const int k0 = isSplit ? (khalf ? Hh : 0) : 0;
        const int k1 = isSplit ? (khalf ? T : Hh) : T;
        const int h = xcd * 2 + hloc;

        const unsigned short* Qg = qkv + (size_t)((0 * HEADS + h) * SEQ) * HD;
        const unsigned short* Kg = qkv + (size_t)((1 * HEADS + h) * SEQ) * HD;
        const unsigned short* VTg = vt + (size_t)h * HD * SEQ;

        const int qbase = qtile * 256 + wave * 32;
        const int qrow = qbase + l32;

        bf16x8 qf[4];
#pragma unroll
        for (int dg = 0; dg < 4; ++dg)
            qf[dg] = *reinterpret_cast<const bf16x8*>(Qg + (size_t)qrow * HD + dg * 16 + hi * 8);

        f32x16 oa[2] = {};
        float m_r = -1e30f, l_r = 0.f;

        auto STAGE = [&](int b, int kt) {
#pragma unroll
            for (int i = 0; i < 2; ++i) {
                int base = wave * 2048 + i * 1024;
                int byte = base + lane * 16;
                int krow = byte >> 7;
                int kc8 = ((byte >> 4) & 7) ^ (krow & 7);
                gload16(Kg + (size_t)(kt * 128 + krow) * HD + kc8 * 8, (char*)k_lds[b] + base);
                int fr = byte >> 7;
                int h64 = fr >> 6, vd = fr & 63;
                int vc8 = ((byte >> 4) & 7) ^ (vd & 7);
                gload16(VTg + (size_t)vd * SEQ + kt * 128 + h64 * 64 + vc8 * 8,
                        (char*)v_lds[b] + base);
            }
        };

        STAGE(0, k0);

        for (int kt = k0; kt < k1; ++kt) {
            const int cur = (kt - k0) & 1;
            asm volatile("s_waitcnt vmcnt(0)" ::: "memory");
            __builtin_amdgcn_s_barrier();
            if (kt + 1 < k1) STAGE(cur ^ 1, kt + 1);

#pragma unroll
            for (int hh = 0; hh < 2; ++hh) {
                if (hh && (kt * 128 + 64) > (qbase + 31)) break;

                f32x16 s[2] = {};
                __builtin_amdgcn_s_setprio(1);
#pragma unroll
                for (int g = 0; g < 2; ++g) {
                    int row = hh * 64 + g * 32 + l32;
#pragma unroll
                    for (int dg = 0; dg < 4; ++dg) {
                        bf16x8 kf = *reinterpret_cast<const bf16x8*>(
                            (char*)k_lds[cur] + row * 128 + ((dg * 32 + hi * 16) ^ rsw));
                        s[g] = __builtin_amdgcn_mfma_f32_32x32x16_bf16(kf, qf[dg], s[g], 0, 0, 0);
                    }
                }
                __builtin_amdgcn_s_setprio(0);

                if (kt * 128 + hh * 64 + 63 > qbase) {
#pragma unroll
                    for (int g = 0; g < 2; ++g)
#pragma unroll
                        for (int r = 0; r < 16; ++r) {
                            int kv = kt * 128 + hh * 64 + g * 32 + (r & 3) + 8 * (r >> 2) + 4 * hi;
                            if (kv > qrow) s[g][r] = -1e30f;
                        }
                }

                float ma = -1e30f, mb = -1e30f, mc = -1e30f, md = -1e30f;
#pragma unroll
                for (int r = 0; r < 16; r += 4) {
                    ma = fmaxf(ma, fmaxf(s[0][r], s[1][r]));
                    mb = fmaxf(mb, fmaxf(s[0][r + 1], s[1][r + 1]));
                    mc = fmaxf(mc, fmaxf(s[0][r + 2], s[1][r + 2]));
                    md = fmaxf(md, fmaxf(s[0][r + 3], s[1][r + 3]));
                }
                float mx = fmaxf(fmaxf(ma, mb), fmaxf(mc, md));
                mx = fmaxf(mx, __shfl_xor(mx, 32));

                if (__any(mx > m_r + 8.0f)) {
                    float mnew = fmaxf(m_r, mx);
                    float alpha = __builtin_amdgcn_exp2f(m_r - mnew);
                    m_r = mnew;
#pragma unroll
                    for (int r = 0; r < 16; ++r) { oa[0][r] *= alpha; oa[1][r] *= alpha; }
                    l_r *= alpha;
                }

#pragma unroll
                for (int g = 0; g < 2; ++g)
#pragma unroll
                    for (int r = 0; r < 16; ++r) s[g][r] = __builtin_amdgcn_exp2f(s[g][r] - m_r);

                float ra = 0.f, rb = 0.f;
#pragma unroll
                for (int r = 0; r < 16; r += 2) {
                    ra += s[0][r] + s[1][r];
                    rb += s[0][r + 1] + s[1][r + 1];
                }
                float rs = ra + rb;
                rs += __shfl_xor(rs, 32);
                l_r += rs;

                __builtin_amdgcn_s_setprio(1);
#pragma unroll
                for (int g = 0; g < 2; ++g) {
                    u32x4 pfw[2];
#pragma unroll
                    for (int u = 0; u < 2; ++u) {
                        unsigned wA = cvt_pk_bf16(s[g][8 * u + 0], s[g][8 * u + 1]);
                        unsigned wC = cvt_pk_bf16(s[g][8 * u + 2], s[g][8 * u + 3]);
                        unsigned wB = cvt_pk_bf16(s[g][8 * u + 4], s[g][8 * u + 5]);
                        unsigned wD = cvt_pk_bf16(s[g][8 * u + 6], s[g][8 * u + 7]);
                        unsigned wAx = __shfl_xor((int)wA, 32), wBx = __shfl_xor((int)wB, 32);
                        unsigned wCx = __shfl_xor((int)wC, 32), wDx = __shfl_xor((int)wD, 32);
                        pfw[u][0] = hi ? wBx : wA;
                        pfw[u][1] = hi ? wDx : wC;
                        pfw[u][2] = hi ? wB : wAx;
                        pfw[u][3] = hi ? wD : wCx;
                    }
#pragma unroll
                    for (int u = 0; u < 2; ++u) {
                        bf16x8 pf = __builtin_bit_cast(bf16x8, pfw[u]);
                        int ks = g * 2 + u;
#pragma unroll
                        for (int dg = 0; dg < 2; ++dg) {
                            bf16x8 vf = *reinterpret_cast<const bf16x8*>(
                                (char*)v_lds[cur][hh] + (dg * 32 + l32) * 128 + ((ks * 32 + hi * 16) ^ rsw));
                            oa[dg] = __builtin_amdgcn_mfma_f32_32x32x16_bf16(vf, pf, oa[dg], 0, 0, 0);
                        }
                    }
                }
                __builtin_amdgcn_s_setprio(0);
            }
        }

        const int ql = wave * 32 + l32;
        if (isSplit) {
            int sidx = (h * 12 + (qtile - 4)) * 2 + khalf;
            unsigned short* Op = pO + (size_t)sidx * 16384;
#pragma unroll
            for (int dg = 0; dg < 2; ++dg)
#pragma unroll
                for (int rq = 0; rq < 4; ++rq) {
                    ushort4 ov;
                    ov.x = f2bf(oa[dg][4 * rq + 0]);
                    ov.y = f2bf(oa[dg][4 * rq + 1]);
                    ov.z = f2bf(oa[dg][4 * rq + 2]);
                    ov.w = f2bf(oa[dg][4 * rq + 3]);
                    *reinterpret_cast<ushort4*>(Op + ql * 64 + dg * 32 + 8 * rq + 4 * hi) = ov;
                }
            if (hi == 0) {
                lmf[sidx * 512 + ql] = l_r;
                lmf[sidx * 512 + 256 + ql] = m_r;
            }
        } else {
            float inv = 1.0f / l_r;
            unsigned short* orow = attnout + (size_t)(qtile * 256 + ql) * DMODEL + h * HD;
#pragma unroll
            for (int dg = 0; dg < 2; ++dg)
#pragma unroll
                for (int rq = 0; rq < 4; ++rq) {
                    ushort4 ov;
                    ov.x = f2bf(oa[dg][4 * rq + 0] * inv);
                    ov.y = f2bf(oa[dg][4 * rq + 1] * inv);
                    ov.z = f2bf(oa[dg][4 * rq + 2] * inv);
                    ov.w = f2bf(oa[dg][4 * rq + 3] * inv);
                    *reinterpret_cast<ushort4*>(orow + dg * 32 + 8 * rq + 4 * hi) = ov;
                }
        }
    }
}

// ---------------- merge K-half partials (qtiles 4..15, 256-row) ----------------
__global__ __launch_bounds__(256) void merge_kernel(const unsigned short* __restrict__ pO,
                                                    const float* __restrict__ lmf,
                                                    unsigned short* __restrict__ attnout) {
    int idx = blockIdx.x * 256 + threadIdx.x;
    if (idx >= 16 * 12 * 2048) return;
    int h = idx / (12 * 2048);
    int r = idx % (12 * 2048);
    int qt = r >> 11;
    int rr = r & 2047;
    int q = rr >> 3, d8 = rr & 7;

    int s0 = (h * 12 + qt) * 2;
    float l0 = lmf[s0 * 512 + q],       m0 = lmf[s0 * 512 + 256 + q];
    float l1 = lmf[(s0 + 1) * 512 + q], m1 = lmf[(s0 + 1) * 512 + 256 + q];
    float m = fmaxf(m0, m1);
    float a0 = __builtin_amdgcn_exp2f(m0 - m), a1 = __builtin_amdgcn_exp2f(m1 - m);
    float L = l0 * a0 + l1 * a1;
    float c0 = a0 / L, c1 = a1 / L;

    const unsigned short* O0 = pO + (size_t)s0 * 16384 + q * 64 + d8 * 8;
    const unsigned short* O1 = O0 + 16384;
    short8 v0 = *reinterpret_cast<const short8*>(O0);
    short8 v1 = *reinterpret_cast<const short8*>(O1);
    short8 o;
#pragma unroll
    for (int j = 0; j < 8; ++j) {
        float val = bf2f((unsigned short)v0[j]) * c0 + bf2f((unsigned short)v1[j]) * c1;
        o[j] = (short)f2bf(val);
    }
    int qtile = qt + 4;
    *reinterpret_cast<short8*>(attnout + (size_t)(qtile * 256 + q) * DMODEL + h * HD + d8 * 8) = o;
}

extern "C" void kernel_launch(void* const* d_in, const int* in_sizes, int n_in,
                              void* d_out, int out_size, void* d_ws, size_t ws_size,
                              hipStream_t stream) {
    const float* x = (const float*)d_in[0];
    const int* pos = (const int*)d_in[1];
    const float* wqkv = (const float*)d_in[2];
    const float* wo = (const float*)d_in[3];
    float* out = (float*)d_out;

    unsigned short* xb = (unsigned short*)d_ws;                       // 8MB
    unsigned short* wqkvb = xb + (size_t)SEQ * DMODEL;                // 6MB
    unsigned short* wob = wqkvb + (size_t)NQKV * DMODEL;              // 2MB
    unsigned short* qkvp = wob + (size_t)DMODEL * DMODEL;             // 24MB (part2 = V^T [h][d][s])
    unsigned short* vtp = qkvp + (size_t)2 * HEADS * SEQ * HD;        // V^T region inside qkvp
    float* csT = (float*)(qkvp + (size_t)3 * HEADS * SEQ * HD);       // 512KB
    float* snT = csT + SEQ * 32;                                      // 512KB
    unsigned short* attnb = (unsigned short*)(snT + SEQ * 32);        // 8MB

    // split-K scratch in xb/wqkvb (dead after gemm1): qcnt | lmf 768KB | pO 12MB
    char* sbase = (char*)d_ws;
    int* qcnt = (int*)sbase;
    float* lmf = (float*)(sbase + 1024);
    unsigned short* pO = (unsigned short*)(sbase + (1 << 20));

    f2bf_all<<<2048, 256, 0, stream>>>(x, wqkv, wo, pos, xb, csT, snT);

    dim3 g1(SEQ / 128, NQKV / 128);
    gemm_bt<0><<<g1, 256, 0, stream>>>(xb, wqkvb, nullptr, qkvp, vtp, csT, snT, SEQ, NQKV, DMODEL);

    hipMemsetAsync(qcnt, 0, 64, stream);
    attn_kernel<<<512, 512, 0, stream>>>(qkvp, vtp, attnb, qcnt, pO, lmf);
    merge_kernel<<<(16 * 12 * 2048 + 255) / 256, 256, 0, stream>>>(pO, lmf, attnb);

    dim3 g2(SEQ / 128, DMODEL / 128);
    gemm_bt<1><<<g2, 256, 0, stream>>>(attnb, wob, out, nullptr, nullptr, nullptr, nullptr, SEQ, DMODEL, DMODEL);
}

// Round 21
// 137.057 us; speedup vs baseline: 1.1531x; 1.0038x over previous
//
#include <hip/hip_runtime.h>

#define SEQ 4096
#define DMODEL 1024
#define HEADS 16
#define HD 64
#define NQKV 3072

typedef __attribute__((ext_vector_type(8))) __bf16 bf16x8;
typedef __attribute__((ext_vector_type(4))) __bf16 bf16x4;
typedef __attribute__((ext_vector_type(8))) short short8;
typedef __attribute__((ext_vector_type(4))) float f32x4;
typedef __attribute__((ext_vector_type(16))) float f32x16;
typedef __attribute__((ext_vector_type(4))) unsigned int u32x4;

__device__ __forceinline__ unsigned short f2bf(float f) {
    unsigned u = __builtin_bit_cast(unsigned, f);
    return (unsigned short)((u + 0x7fffu + ((u >> 16) & 1u)) >> 16);
}
__device__ __forceinline__ float bf2f(unsigned short h) {
    return __builtin_bit_cast(float, (unsigned)h << 16);
}
__device__ __forceinline__ unsigned cvt_pk_bf16(float lo, float hi) {
    unsigned r;
    asm("v_cvt_pk_bf16_f32 %0, %1, %2" : "=v"(r) : "v"(lo), "v"(hi));
    return r;
}

__device__ __forceinline__ void gload16(const void* g, void* l) {
    __builtin_amdgcn_global_load_lds(
        (const __attribute__((address_space(1))) unsigned int*)g,
        (__attribute__((address_space(3))) unsigned int*)l, 16, 0, 0);
}

// per-head task table, LPT (length-desc). bit6=split, bit5=khalf, bits0-4=qtile(256-row)
#define TS(qt, kh) (0x40 | ((kh) << 5) | (qt))
__device__ __constant__ unsigned char TASKS[28] = {
    TS(15,0), TS(15,1), TS(14,0), TS(14,1), TS(13,0), TS(13,1),
    TS(12,0), TS(12,1), TS(11,0), TS(11,1), TS(10,0), TS(10,1),
    TS(9,0),  TS(9,1),  TS(8,0),  TS(8,1),  TS(7,0),  TS(7,1),
    3,        TS(6,0),  TS(6,1),  2,        TS(5,0),  TS(5,1),
    TS(4,0),  TS(4,1),  1,        0
};

// ---------------- fp32 -> bf16 convert + RoPE cos/sin table gen ----------------
__global__ void f2bf_all(const float* __restrict__ x, const float* __restrict__ wqkv,
                         const float* __restrict__ wo, const int* __restrict__ pos,
                         unsigned short* __restrict__ dst,
                         float* __restrict__ csT, float* __restrict__ snT) {
    const int N0 = SEQ * DMODEL / 4;
    const int N1 = N0 + NQKV * DMODEL / 4;
    const int NT = N1 + DMODEL * DMODEL / 4;
    int i = blockIdx.x * 256 + threadIdx.x;
    int stride = gridDim.x * 256;
    for (; i < NT; i += stride) {
        const float4* src;
        if (i < N0)      src = reinterpret_cast<const float4*>(x) + i;
        else if (i < N1) src = reinterpret_cast<const float4*>(wqkv) + (i - N0);
        else             src = reinterpret_cast<const float4*>(wo) + (i - N1);
        float4 f = *src;
        ushort4 o;
        o.x = f2bf(f.x); o.y = f2bf(f.y); o.z = f2bf(f.z); o.w = f2bf(f.w);
        reinterpret_cast<ushort4*>(dst)[i] = o;
    }
    const float kk = -13.287712379549449f / 32.0f;  // -log2(10000)/32
    for (int idx = blockIdx.x * 256 + threadIdx.x; idx < SEQ * 32; idx += stride) {
        int s = idx >> 5, fi = idx & 31;
        float p = (float)pos[s];
        float ang = p * exp2f((float)fi * kk);
        float sn_, cs_;
        sincosf(ang, &sn_, &cs_);
        csT[idx] = cs_;
        snT[idx] = sn_;
    }
}

// ---------------- bf16 GEMM, C = A(MxK) * B(NxK)^T, fused QKV epilogue ----------------
// XCD-swizzled 1-D grid: xcd owns 4 contiguous bm rows x all 24 bn.
__global__ __launch_bounds__(256) void gemm_qkv(const unsigned short* __restrict__ A,
                                                const unsigned short* __restrict__ B,
                                                unsigned short* __restrict__ outB,
                                                unsigned short* __restrict__ vtp,
                                                const float* __restrict__ csT,
                                                const float* __restrict__ snT,
                                                int M, int N, int K) {
    alignas(16) __shared__ unsigned short a_lds[2][128 * 32];
    alignas(16) __shared__ unsigned short b_lds[2][128 * 32];
    __shared__ unsigned short vtile[4][16][72];
    const int tid = threadIdx.x;
    const int wave = tid >> 6, lane = tid & 63;
    const int l16 = lane & 15, g = lane >> 4;
    const int wr = wave >> 1, wc = wave & 1;

    // XCD swizzle: t = xcd*96 + idx ; bm = t/24 (4 rows per XCD), bn = t%24
    const int bid = blockIdx.x;
    const int t = (bid & 7) * 96 + (bid >> 3);
    const int bm = t / 24, bn = t % 24;

    const int lrow = lane >> 2;
    const int lcol = (lane & 3) * 8;

    const unsigned short* Ag = A + (size_t)(bm * 128 + lrow) * K + lcol;
    const unsigned short* Bg = B + (size_t)(bn * 128 + lrow) * K + lcol;

    f32x4 acc[4][4] = {};
    const int NS = K / 32;

    auto STAGE = [&](int b, int ks) {
#pragma unroll
        for (int j = 0; j < 2; ++j) {
            int chunk = wave * 2 + j;
            gload16(Ag + (size_t)(chunk * 16) * K + ks * 32, a_lds[b] + chunk * 512);
            gload16(Bg + (size_t)(chunk * 16) * K + ks * 32, b_lds[b] + chunk * 512);
        }
    };

    STAGE(0, 0);

    for (int ks = 0; ks < NS; ++ks) {
        const int cur = ks & 1;
        asm volatile("s_waitcnt vmcnt(0)" ::: "memory");
        __builtin_amdgcn_s_barrier();
        if (ks + 1 < NS) STAGE(cur ^ 1, ks + 1);

        bf16x8 af[4], bfr[4];
#pragma unroll
        for (int m = 0; m < 4; ++m)
            af[m] = *reinterpret_cast<const bf16x8*>(a_lds[cur] + (wr * 64 + m * 16 + l16) * 32 + g * 8);
#pragma unroll
        for (int n = 0; n < 4; ++n)
            bfr[n] = *reinterpret_cast<const bf16x8*>(b_lds[cur] + (wc * 64 + n * 16 + l16) * 32 + g * 8);
        __builtin_amdgcn_s_setprio(1);
#pragma unroll
        for (int m = 0; m < 4; ++m)
#pragma unroll
            for (int n = 0; n < 4; ++n)
                acc[m][n] = __builtin_amdgcn_mfma_f32_16x16x32_bf16(af[m], bfr[n], acc[m][n], 0, 0, 0);
        __builtin_amdgcn_s_setprio(0);
    }

    const float QS = 0.125f * 1.4426950408889634f;  // softmax scale * log2e
#pragma unroll
    for (int n = 0; n < 4; ++n) {
        const int col = bn * 128 + wc * 64 + n * 16 + l16;
        const int part = col >> 10;
        const int hh = (col >> 6) & 15;
        if (part < 2) {
            const int fi = (col & 63) >> 1;
            const float sc = (part == 0) ? QS : 1.0f;
            const bool odd = (col & 1) != 0;
#pragma unroll
            for (int m = 0; m < 4; ++m)
#pragma unroll
                for (int r = 0; r < 4; ++r) {
                    int row = bm * 128 + wr * 64 + m * 16 + g * 4 + r;
                    float v = acc[m][n][r];
                    float pp = __shfl_xor(v, 1);
                    float cs_ = csT[row * 32 + fi];
                    float sn_ = snT[row * 32 + fi];
                    float out = odd ? (pp * sn_ + v * cs_) : (v * cs_ - pp * sn_);
                    outB[(size_t)((part * HEADS + hh) * SEQ + row) * HD + (col & 63)] = f2bf(out * sc);
                }
        } else {
#pragma unroll
            for (int m = 0; m < 4; ++m)
#pragma unroll
                for (int r = 0; r < 4; ++r)
                    vtile[wave][l16][m * 16 + g * 4 + r] = f2bf(acc[m][n][r]);
#pragma unroll
            for (int dd = 0; dd < 16; ++dd) {
                int dg = ((col & 63) & ~15) + dd;
                vtp[(size_t)(hh * HD + dg) * SEQ + bm * 128 + wr * 64 + lane] =
                    vtile[wave][dd][lane];
            }
        }
    }
}

// ---------------- output GEMM, C = A(MxK) * B(NxK)^T fp32, 128x64 tile ----------------
// 512 blocks -> 2 blocks/CU (vs 256 at BN=128): backfill for the barrier-locked schedule.
__global__ __launch_bounds__(256) void gemm_out(const unsigned short* __restrict__ A,
                                                const unsigned short* __restrict__ B,
                                                float* __restrict__ outF,
                                                int M, int N, int K) {
    alignas(16) __shared__ unsigned short a_lds[2][128 * 32];
    alignas(16) __shared__ unsigned short b_lds[2][64 * 32];
    const int tid = threadIdx.x;
    const int wave = tid >> 6, lane = tid & 63;
    const int l16 = lane & 15, g = lane >> 4;
    const int wr = wave >> 1, wc = wave & 1;     // waves 2x2 over 64x32 sub-tiles
    const int bm = blockIdx.x, bn = blockIdx.y;

    const int lrow = lane >> 2;
    const int lcol = (lane & 3) * 8;

    const unsigned short* Ag = A + (size_t)(bm * 128 + lrow) * K + lcol;
    const unsigned short* Bg = B + (size_t)(bn * 64 + lrow) * K + lcol;

    f32x4 acc[4][2] = {};
    const int NS = K / 32;

    auto STAGE = [&](int b, int ks) {
#pragma unroll
        for (int j = 0; j < 2; ++j) {
            int chunk = wave * 2 + j;
            gload16(Ag + (size_t)(chunk * 16) * K + ks * 32, a_lds[b] + chunk * 512);
        }
        gload16(Bg + (size_t)(wave * 16) * K + ks * 32, b_lds[b] + wave * 512);
    };

    STAGE(0, 0);

    for (int ks = 0; ks < NS; ++ks) {
        const int cur = ks & 1;
        asm volatile("s_waitcnt vmcnt(0)" ::: "memory");
        __builtin_amdgcn_s_barrier();
        if (ks + 1 < NS) STAGE(cur ^ 1, ks + 1);

        bf16x8 af[4], bfr[2];
#pragma unroll
        for (int m = 0; m < 4; ++m)
            af[m] = *reinterpret_cast<const bf16x8*>(a_lds[cur] + (wr * 64 + m * 16 + l16) * 32 + g * 8);
#pragma unroll
        for (int n = 0; n < 2; ++n)
            bfr[n] = *reinterpret_cast<const bf16x8*>(b_lds[cur] + (wc * 32 + n * 16 + l16) * 32 + g * 8);
        __builtin_amdgcn_s_setprio(1);
#pragma unroll
        for (int m = 0; m < 4; ++m)
#pragma unroll
            for (int n = 0; n < 2; ++n)
                acc[m][n] = __builtin_amdgcn_mfma_f32_16x16x32_bf16(af[m], bfr[n], acc[m][n], 0, 0, 0);
        __builtin_amdgcn_s_setprio(0);
    }

#pragma unroll
    for (int m = 0; m < 4; ++m)
#pragma unroll
        for (int n = 0; n < 2; ++n)
#pragma unroll
            for (int r = 0; r < 4; ++r) {
                int row = bm * 128 + wr * 64 + m * 16 + g * 4 + r;
                int col = bn * 64 + wc * 32 + n * 16 + l16;
                outF[(size_t)row * N + col] = acc[m][n][r];
            }
}

// ---------------- causal flash attention (R18, unchanged) ----------------
__global__ __launch_bounds__(512) void attn_kernel(const unsigned short* __restrict__ qkv,
                                                   const unsigned short* __restrict__ vt,
                                                   unsigned short* __restrict__ attnout,
                                                   int* __restrict__ qcnt,
                                                   unsigned short* __restrict__ pO,
                                                   float* __restrict__ lmf) {
    const int xcd = blockIdx.x & 7;
    const int tid = threadIdx.x;
    const int wave = tid >> 6, lane = tid & 63;
    const int l32 = lane & 31, hi = lane >> 5;

    alignas(16) __shared__ unsigned short k_lds[2][128 * 64];
    alignas(16) __shared__ unsigned short v_lds[2][2][64 * 64];
    __shared__ int slot_sh;

    const int rsw = (l32 & 7) << 4;

    for (;;) {
        if (tid == 0) slot_sh = atomicAdd(&qcnt[xcd], 1);
        __syncthreads();
        const int t = slot_sh;
        __syncthreads();
        if (t >= 56) break;

        const int hloc = t & 1;
        const unsigned char e = TASKS[t >> 1];
        const int qtile = e & 31;
        const int khalf = (e >> 5) & 1;
        const bool isSplit = (e >> 6) != 0;
        const int T = 2 * qtile + 2, Hh = qtile + 1;
        const int k0 = isSplit ? (khalf ? Hh : 0) : 0;
        const int k1 = isSplit ? (khalf ? T : Hh) : T;
        const int h = xcd * 2 + hloc;

        const unsigned short* Qg = qkv + (size_t)((0 * HEADS + h) * SEQ) * HD;
        const unsigned short* Kg = qkv + (size_t)((1 * HEADS + h) * SEQ) * HD;
        const unsigned short* VTg = vt + (size_t)h * HD * SEQ;

        const int qbase = qtile * 256 + wave * 32;
        const int qrow = qbase + l32;

        bf16x8 qf[4];
#pragma unroll
        for (int dg = 0; dg < 4; ++dg)
            qf[dg] = *reinterpret_cast<const bf16x8*>(Qg + (size_t)qrow * HD + dg * 16 + hi * 8);

        f32x16 oa[2] = {};
        float m_r = -1e30f, l_r = 0.f;

        auto STAGE = [&](int b, int kt) {
#pragma unroll
            for (int i = 0; i < 2; ++i) {
                int base = wave * 2048 + i * 1024;
                int byte = base + lane * 16;
                int krow = byte >> 7;
                int kc8 = ((byte >> 4) & 7) ^ (krow & 7);
                gload16(Kg + (size_t)(kt * 128 + krow) * HD + kc8 * 8, (char*)k_lds[b] + base);
                int fr = byte >> 7;
                int h64 = fr >> 6, vd = fr & 63;
                int vc8 = ((byte >> 4) & 7) ^ (vd & 7);
                gload16(VTg + (size_t)vd * SEQ + kt * 128 + h64 * 64 + vc8 * 8,
                        (char*)v_lds[b] + base);
            }
        };

        STAGE(0, k0);

        for (int kt = k0; kt < k1; ++kt) {
            const int cur = (kt - k0) & 1;
            asm volatile("s_waitcnt vmcnt(0)" ::: "memory");
            __builtin_amdgcn_s_barrier();
            if (kt + 1 < k1) STAGE(cur ^ 1, kt + 1);

#pragma unroll
            for (int hh = 0; hh < 2; ++hh) {
                if (hh && (kt * 128 + 64) > (qbase + 31)) break;

                f32x16 s[2] = {};
                __builtin_amdgcn_s_setprio(1);
#pragma unroll
                for (int g = 0; g < 2; ++g) {
                    int row = hh * 64 + g * 32 + l32;
#pragma unroll
                    for (int dg = 0; dg < 4; ++dg) {
                        bf16x8 kf = *reinterpret_cast<const bf16x8*>(
                            (char*)k_lds[cur] + row * 128 + ((dg * 32 + hi * 16) ^ rsw));
                        s[g] = __builtin_amdgcn_mfma_f32_32x32x16_bf16(kf, qf[dg], s[g], 0, 0, 0);
                    }
                }
                __builtin_amdgcn_s_setprio(0);

                if (kt * 128 + hh * 64 + 63 > qbase) {
#pragma unroll
                    for (int g = 0; g < 2; ++g)
#pragma unroll
                        for (int r = 0; r < 16; ++r) {
                            int kv = kt * 128 + hh * 64 + g * 32 + (r & 3) + 8 * (r >> 2) + 4 * hi;
                            if (kv > qrow) s[g][r] = -1e30f;
                        }
                }

                float ma = -1e30f, mb = -1e30f, mc = -1e30f, md = -1e30f;
#pragma unroll
                for (int r = 0; r < 16; r += 4) {
                    ma = fmaxf(ma, fmaxf(s[0][r], s[1][r]));
                    mb = fmaxf(mb, fmaxf(s[0][r + 1], s[1][r + 1]));
                    mc = fmaxf(mc, fmaxf(s[0][r + 2], s[1][r + 2]));
                    md = fmaxf(md, fmaxf(s[0][r + 3], s[1][r + 3]));
                }
                float mx = fmaxf(fmaxf(ma, mb), fmaxf(mc, md));
                mx = fmaxf(mx, __shfl_xor(mx, 32));

                if (__any(mx > m_r + 8.0f)) {
                    float mnew = fmaxf(m_r, mx);
                    float alpha = __builtin_amdgcn_exp2f(m_r - mnew);
                    m_r = mnew;
#pragma unroll
                    for (int r = 0; r < 16; ++r) { oa[0][r] *= alpha; oa[1][r] *= alpha; }
                    l_r *= alpha;
                }

#pragma unroll
                for (int g = 0; g < 2; ++g)
#pragma unroll
                    for (int r = 0; r < 16; ++r) s[g][r] = __builtin_amdgcn_exp2f(s[g][r] - m_r);

                float ra = 0.f, rb = 0.f;
#pragma unroll
                for (int r = 0; r < 16; r += 2) {
                    ra += s[0][r] + s[1][r];
                    rb += s[0][r + 1] + s[1][r + 1];
                }
                float rs = ra + rb;
                rs += __shfl_xor(rs, 32);
                l_r += rs;

                __builtin_amdgcn_s_setprio(1);
#pragma unroll
                for (int g = 0; g < 2; ++g) {
                    u32x4 pfw[2];
#pragma unroll
                    for (int u = 0; u < 2; ++u) {
                        unsigned wA = cvt_pk_bf16(s[g][8 * u + 0], s[g][8 * u + 1]);
                        unsigned wC = cvt_pk_bf16(s[g][8 * u + 2], s[g][8 * u + 3]);
                        unsigned wB = cvt_pk_bf16(s[g][8 * u + 4], s[g][8 * u + 5]);
                        unsigned wD = cvt_pk_bf16(s[g][8 * u + 6], s[g][8 * u + 7]);
                        unsigned wAx = __shfl_xor((int)wA, 32), wBx = __shfl_xor((int)wB, 32);
                        unsigned wCx = __shfl_xor((int)wC, 32), wDx = __shfl_xor((int)wD, 32);
                        pfw[u][0] = hi ? wBx : wA;
                        pfw[u][1] = hi ? wDx : wC;
                        pfw[u][2] = hi ? wB : wAx;
                        pfw[u][3] = hi ? wD : wCx;
                    }
#pragma unroll
                    for (int u = 0; u < 2; ++u) {
                        bf16x8 pf = __builtin_bit_cast(bf16x8, pfw[u]);
                        int ks = g * 2 + u;
#pragma unroll
                        for (int dg = 0; dg < 2; ++dg) {
                            bf16x8 vf = *reinterpret_cast<const bf16x8*>(
                                (char*)v_lds[cur][hh] + (dg * 32 + l32) * 128 + ((ks * 32 + hi * 16) ^ rsw));
                            oa[dg] = __builtin_amdgcn_mfma_f32_32x32x16_bf16(vf, pf, oa[dg], 0, 0, 0);
                        }
                    }
                }
                __builtin_amdgcn_s_setprio(0);
            }
        }

        const int ql = wave * 32 + l32;
        if (isSplit) {
            int sidx = (h * 12 + (qtile - 4)) * 2 + khalf;
            unsigned short* Op = pO + (size_t)sidx * 16384;
#pragma unroll
            for (int dg = 0; dg < 2; ++dg)
#pragma unroll
                for (int rq = 0; rq < 4; ++rq) {
                    ushort4 ov;
                    ov.x = f2bf(oa[dg][4 * rq + 0]);
                    ov.y = f2bf(oa[dg][4 * rq + 1]);
                    ov.z = f2bf(oa[dg][4 * rq + 2]);
                    ov.w = f2bf(oa[dg][4 * rq + 3]);
                    *reinterpret_cast<ushort4*>(Op + ql * 64 + dg * 32 + 8 * rq + 4 * hi) = ov;
                }
            if (hi == 0) {
                lmf[sidx * 512 + ql] = l_r;
                lmf[sidx * 512 + 256 + ql] = m_r;
            }
        } else {
            float inv = 1.0f / l_r;
            unsigned short* orow = attnout + (size_t)(qtile * 256 + ql) * DMODEL + h * HD;
#pragma unroll
            for (int dg = 0; dg < 2; ++dg)
#pragma unroll
                for (int rq = 0; rq < 4; ++rq) {
                    ushort4 ov;
                    ov.x = f2bf(oa[dg][4 * rq + 0] * inv);
                    ov.y = f2bf(oa[dg][4 * rq + 1] * inv);
                    ov.z = f2bf(oa[dg][4 * rq + 2] * inv);
                    ov.w = f2bf(oa[dg][4 * rq + 3] * inv);
                    *reinterpret_cast<ushort4*>(orow + dg * 32 + 8 * rq + 4 * hi) = ov;
                }
        }
    }
}

// ---------------- merge K-half partials (qtiles 4..15, 256-row) ----------------
__global__ __launch_bounds__(256) void merge_kernel(const unsigned short* __restrict__ pO,
                                                    const float* __restrict__ lmf,
                                                    unsigned short* __restrict__ attnout) {
    int idx = blockIdx.x * 256 + threadIdx.x;
    if (idx >= 16 * 12 * 2048) return;
    int h = idx / (12 * 2048);
    int r = idx % (12 * 2048);
    int qt = r >> 11;
    int rr = r & 2047;
    int q = rr >> 3, d8 = rr & 7;

    int s0 = (h * 12 + qt) * 2;
    float l0 = lmf[s0 * 512 + q],       m0 = lmf[s0 * 512 + 256 + q];
    float l1 = lmf[(s0 + 1) * 512 + q], m1 = lmf[(s0 + 1) * 512 + 256 + q];
    float m = fmaxf(m0, m1);
    float a0 = __builtin_amdgcn_exp2f(m0 - m), a1 = __builtin_amdgcn_exp2f(m1 - m);
    float L = l0 * a0 + l1 * a1;
    float c0 = a0 / L, c1 = a1 / L;

    const unsigned short* O0 = pO + (size_t)s0 * 16384 + q * 64 + d8 * 8;
    const unsigned short* O1 = O0 + 16384;
    short8 v0 = *reinterpret_cast<const short8*>(O0);
    short8 v1 = *reinterpret_cast<const short8*>(O1);
    short8 o;
#pragma unroll
    for (int j = 0; j < 8; ++j) {
        float val = bf2f((unsigned short)v0[j]) * c0 + bf2f((unsigned short)v1[j]) * c1;
        o[j] = (short)f2bf(val);
    }
    int qtile = qt + 4;
    *reinterpret_cast<short8*>(attnout + (size_t)(qtile * 256 + q) * DMODEL + h * HD + d8 * 8) = o;
}

extern "C" void kernel_launch(void* const* d_in, const int* in_sizes, int n_in,
                              void* d_out, int out_size, void* d_ws, size_t ws_size,
                              hipStream_t stream) {
    const float* x = (const float*)d_in[0];
    const int* pos = (const int*)d_in[1];
    const float* wqkv = (const float*)d_in[2];
    const float* wo = (const float*)d_in[3];
    float* out = (float*)d_out;

    unsigned short* xb = (unsigned short*)d_ws;                       // 8MB
    unsigned short* wqkvb = xb + (size_t)SEQ * DMODEL;                // 6MB
    unsigned short* wob = wqkvb + (size_t)NQKV * DMODEL;              // 2MB
    unsigned short* qkvp = wob + (size_t)DMODEL * DMODEL;             // 24MB (part2 = V^T)
    unsigned short* vtp = qkvp + (size_t)2 * HEADS * SEQ * HD;
    float* csT = (float*)(qkvp + (size_t)3 * HEADS * SEQ * HD);       // 512KB
    float* snT = csT + SEQ * 32;                                      // 512KB
    unsigned short* attnb = (unsigned short*)(snT + SEQ * 32);        // 8MB

    // split-K scratch in xb/wqkvb (dead after gemm1): qcnt | lmf 768KB | pO 12MB
    char* sbase = (char*)d_ws;
    int* qcnt = (int*)sbase;
    float* lmf = (float*)(sbase + 1024);
    unsigned short* pO = (unsigned short*)(sbase + (1 << 20));

    f2bf_all<<<2048, 256, 0, stream>>>(x, wqkv, wo, pos, xb, csT, snT);

    gemm_qkv<<<768, 256, 0, stream>>>(xb, wqkvb, qkvp, vtp, csT, snT, SEQ, NQKV, DMODEL);

    hipMemsetAsync(qcnt, 0, 64, stream);
    attn_kernel<<<512, 512, 0, stream>>>(qkvp, vtp, attnb, qcnt, pO, lmf);
    merge_kernel<<<(16 * 12 * 2048 + 255) / 256, 256, 0, stream>>>(pO, lmf, attnb);

    dim3 g2(SEQ / 128, DMODEL / 64);
    gemm_out<<<g2, 256, 0, stream>>>(attnb, wob, out, SEQ, DMODEL, DMODEL);
}